// Round 7
// baseline (273.530 us; speedup 1.0000x reference)
//
#include <hip/hip_runtime.h>
#include <math.h>

// ---------------------------------------------------------------------------
// AttentionEncoder: B=8, S=2048, D=1024, K=64
// Round 7: single-sync K-tile in gemm256 — ONE vmcnt(0)+barrier per K-tile
// (4-phase slack makes the drain free), all 4 half-tile stages front-loaded
// post-barrier, P2-P4 barrier-free so waves drift and overlap ds_read bursts
// with the other wave's MFMA cluster on the same SIMD.
// ---------------------------------------------------------------------------

typedef __bf16 bf16_t;
typedef __bf16 bf16x2_t __attribute__((ext_vector_type(2)));
typedef __bf16 bf16x4_t __attribute__((ext_vector_type(4)));
typedef __bf16 bf16x8_t __attribute__((ext_vector_type(8)));
typedef float  f32x4    __attribute__((ext_vector_type(4)));

#define DEV static __device__ __forceinline__

DEV void gll16(const void* g, void* l) {
  __builtin_amdgcn_global_load_lds(
      (const __attribute__((address_space(1))) void*)g,
      (__attribute__((address_space(3))) void*)l, 16, 0, 0);
}

// ---------------------------------------------------------------------------
// 256x256 tile, BK=64, 512 threads (8 waves as 2Mx4N), double-buffered LDS.
// Per K-tile: {vmcnt(0); barrier; reads P1; stage ALL of t+1; MFMA P1;
// then P2..P4 = reads+lgkm+MFMA with NO barrier}. Safety: buf(t+1)=buf(t-1),
// fully read before every wave's arrival at the P1(t) barrier; tile-t data
// visibility = own vmcnt(0) pre-barrier + barrier.
// MODE: 1 VT (bf16, +bv[row]) ; 3 ATTN (bf16) ; 4 FF (bf16, relu(+b1[col]))
// ---------------------------------------------------------------------------
template <int MODE, int MFAST>
__global__ __launch_bounds__(512, 2) void gemm256(
    const bf16_t* __restrict__ A, const bf16_t* __restrict__ B,
    bf16_t* __restrict__ C, int K, int lda, int ldb, int ldc,
    long sAb, long sBb, long sCb, const float* __restrict__ aux0) {
  // bijective XCD remap (nwg % 8 == 0 for all launches here)
  const int gx = gridDim.x, gy = gridDim.y;
  const int gxy = gx * gy;
  const int nwg = gxy * (int)gridDim.z;
  const int orig = blockIdx.x + gx * blockIdx.y + gxy * blockIdx.z;
  const int lid = (orig & 7) * (nwg >> 3) + (orig >> 3);
  const int bz = lid / gxy;
  const int rem = lid - bz * gxy;
  const int bx = MFAST ? (rem / gy) : (rem % gx);
  const int by = MFAST ? (rem % gy) : (rem / gx);

  A += (long)bz * sAb;
  B += (long)bz * sBb;
  const int m0 = by * 256, n0 = bx * 256;

  // [buf][khalf][256 rows][32 cols]  (16 KB per half, 64 B rows)
  __shared__ bf16_t As[2][2][256 * 32];
  __shared__ bf16_t Bs[2][2][256 * 32];

  const int tid = threadIdx.x;
  const int wid = tid >> 6, l = tid & 63;
  const int wr = wid >> 2, wc = wid & 3;   // 2x4 wave grid; wave tile 128x64
  const int lr = l & 15, lh = l >> 4;

  // staging: thread tid -> LDS row tid>>2, physical slot tid&3 (LINEAR dest).
  // Source fetches LOGICAL slot (tid&3)^((row>>1)&3); (row>>1)&3 == (tid>>3)&3.
  const int sRow = tid >> 2;
  const int sSl = (tid & 3) ^ ((tid >> 3) & 3);
  const bf16_t* Asrc = A + (long)(m0 + sRow) * lda + sSl * 8;
  const bf16_t* Bsrc = B + (long)(n0 + sRow) * ldb + sSl * 8;
  const long aStep = (long)128 * lda, bStep = (long)128 * ldb;

#define STAGE_A(b, h, kt) do { \
    const bf16_t* s_ = Asrc + (kt) * 64 + (h) * 32; \
    gll16(s_,         &As[b][h][tid * 8]); \
    gll16(s_ + aStep, &As[b][h][4096 + tid * 8]); } while (0)
#define STAGE_B(b, h, kt) do { \
    const bf16_t* s_ = Bsrc + (kt) * 64 + (h) * 32; \
    gll16(s_,         &Bs[b][h][tid * 8]); \
    gll16(s_ + bStep, &Bs[b][h][4096 + tid * 8]); } while (0)

  // read swizzle: logical slot lh at row 16m+lr -> physical lh^((lr>>1)&3)
  const int sw = (lh ^ ((lr >> 1) & 3)) * 8;
  const int aOff = (wr * 128 + lr) * 32 + sw;  // + m*512 per m-frag
  const int bOff = (wc * 64 + lr) * 32 + sw;   // + n*512 per n-frag

  f32x4 acc[8][4] = {};
  const int NT = K >> 6;

  // prologue: stage all 4 halves of K-tile 0
  STAGE_A(0, 0, 0); STAGE_B(0, 0, 0); STAGE_A(0, 1, 0); STAGE_B(0, 1, 0);

#define LGKM_FENCE() do { \
    asm volatile("s_waitcnt lgkmcnt(0)" ::: "memory"); \
    __builtin_amdgcn_sched_barrier(0); } while (0)
#define MFMA_LO() do { \
    __builtin_amdgcn_s_setprio(1); \
    _Pragma("unroll") for (int m = 0; m < 4; ++m) \
    _Pragma("unroll") for (int n = 0; n < 4; ++n) \
      acc[m][n] = __builtin_amdgcn_mfma_f32_16x16x32_bf16(aF[m], bF[n], acc[m][n], 0, 0, 0); \
    __builtin_amdgcn_s_setprio(0); } while (0)
#define MFMA_HI() do { \
    __builtin_amdgcn_s_setprio(1); \
    _Pragma("unroll") for (int m = 0; m < 4; ++m) \
    _Pragma("unroll") for (int n = 0; n < 4; ++n) \
      acc[m + 4][n] = __builtin_amdgcn_mfma_f32_16x16x32_bf16(aG[m], bF[n], acc[m + 4][n], 0, 0, 0); \
    __builtin_amdgcn_s_setprio(0); } while (0)

  for (int t = 0; t < NT; ++t) {
    const int p = t & 1, q = p ^ 1;
    bf16x8_t bF[4], aF[4], aG[4];

    // ---- tile sync: the ONLY barrier of the K-tile ----
    asm volatile("s_waitcnt vmcnt(0)" ::: "memory");  // own stages of tile t
    __builtin_amdgcn_s_barrier();                     // publish; gate buf reuse
    __builtin_amdgcn_sched_barrier(0);

    // ---- P1: reads [p][0] lo; front-load ALL stages of t+1; MFMA lo ----
#pragma unroll
    for (int n = 0; n < 4; ++n) bF[n] = *(const bf16x8_t*)&Bs[p][0][bOff + n * 512];
#pragma unroll
    for (int m = 0; m < 4; ++m) aF[m] = *(const bf16x8_t*)&As[p][0][aOff + m * 512];
    if (t + 1 < NT) {
      STAGE_A(q, 0, t + 1); STAGE_B(q, 0, t + 1);
      STAGE_A(q, 1, t + 1); STAGE_B(q, 1, t + 1);
    }
    LGKM_FENCE();
    MFMA_LO();

    // ---- P2: reads [p][0] hi; MFMA hi (no barrier: waves drift) ----
#pragma unroll
    for (int m = 0; m < 4; ++m) aG[m] = *(const bf16x8_t*)&As[p][0][aOff + (m + 4) * 512];
    LGKM_FENCE();
    MFMA_HI();

    // ---- P3: reads [p][1] lo; MFMA lo ----
#pragma unroll
    for (int n = 0; n < 4; ++n) bF[n] = *(const bf16x8_t*)&Bs[p][1][bOff + n * 512];
#pragma unroll
    for (int m = 0; m < 4; ++m) aF[m] = *(const bf16x8_t*)&As[p][1][aOff + m * 512];
    LGKM_FENCE();
    MFMA_LO();

    // ---- P4: reads [p][1] hi; MFMA hi ----
#pragma unroll
    for (int m = 0; m < 4; ++m) aG[m] = *(const bf16x8_t*)&As[p][1][aOff + (m + 4) * 512];
    LGKM_FENCE();
    MFMA_HI();
  }
#undef STAGE_A
#undef STAGE_B
#undef LGKM_FENCE
#undef MFMA_LO
#undef MFMA_HI

  // epilogue: C/D frag col = lane&15, row = (lane>>4)*4 + r  [verified]
  bf16_t* Cb = C + (long)bz * sCb;
  const int rowb = m0 + wr * 128 + lh * 4;
  const int colb = n0 + wc * 64 + lr;
#pragma unroll
  for (int m = 0; m < 8; ++m)
#pragma unroll
    for (int n = 0; n < 4; ++n) {
      const f32x4 v = acc[m][n];
      const int cc = colb + n * 16;
#pragma unroll
      for (int r = 0; r < 4; ++r) {
        const int rr = rowb + m * 16 + r;
        const float val = v[r];
        if constexpr (MODE == 1) {
          Cb[(long)rr * ldc + cc] = (bf16_t)(val + aux0[rr]);
        } else if constexpr (MODE == 3) {
          Cb[(long)rr * ldc + cc] = (bf16_t)val;
        } else {
          Cb[(long)rr * ldc + cc] = (bf16_t)fmaxf(val + aux0[cc], 0.0f);
        }
      }
    }
}

// ---------------------------------------------------------------------------
// 128x128 2-phase kernel (kept for KQ and scores).
// MODE 0: KQ -> bf16, col<64: (v+bk[col])*0.125 else v+bq[col-64]
// MODE 2: SCORE -> bf16, sigmoid(v + rowbias[z*sAux + row])
// ---------------------------------------------------------------------------
template <int MODE, int MFAST>
__global__ __launch_bounds__(256) void gemm_bt(
    const bf16_t* __restrict__ A, const bf16_t* __restrict__ B,
    void* __restrict__ Cv, int M, int N, int K, int lda, int ldb, int ldc,
    long sAb, long sBb, long sCb,
    const float* __restrict__ aux0, const float* __restrict__ aux1, long sAux) {
  const int gx = gridDim.x, gy = gridDim.y;
  const int gxy = gx * gy;
  const int nwg = gxy * (int)gridDim.z;
  const int orig = blockIdx.x + gx * blockIdx.y + gxy * blockIdx.z;
  const int q = nwg >> 3, r8 = nwg & 7;
  const int xcd = orig & 7, seq = orig >> 3;
  const int lid = (xcd < r8 ? xcd * (q + 1) : r8 * (q + 1) + (xcd - r8) * q) + seq;
  const int bz = lid / gxy;
  const int rem = lid - bz * gxy;
  const int bx = MFAST ? (rem / gy) : (rem % gx);
  const int by = MFAST ? (rem % gy) : (rem / gx);

  A += (long)bz * sAb;
  B += (long)bz * sBb;
  const float* a0 = (MODE == 2) ? (aux0 + (long)bz * sAux) : aux0;

  const int m0 = by * 128;
  const int n0 = bx * 128;

  __shared__ bf16_t As[2][128 * 32];
  __shared__ bf16_t Bs[2][128 * 32];

  const int tid = threadIdx.x;
  const int w = tid >> 6, l = tid & 63;
  const int wr = w >> 1, wc = w & 1;
  const int lr = l & 15, lh = l >> 4;

  const int srow = l >> 2;
  const int scol = (((l & 3) ^ (srow & 3)) << 3);

  f32x4 acc[4][4] = {};

  auto stage = [&](int buf, int k0) {
#pragma unroll
    for (int half = 0; half < 2; ++half) {
      const int i = 2 * w + half;
      const int row = (i << 4) + srow;
      gll16(A + (long)(m0 + row) * lda + k0 + scol, &As[buf][i << 9]);
      gll16(B + (long)(n0 + row) * ldb + k0 + scol, &Bs[buf][i << 9]);
    }
  };

  stage(0, 0);
  __syncthreads();
  int cur = 0;
  const int sw = ((lh ^ (lr & 3)) << 3);

  for (int k0 = 0; k0 < K; k0 += 32) {
    if (k0 + 32 < K) stage(cur ^ 1, k0 + 32);

    bf16x8_t af[4], bfm[4];
#pragma unroll
    for (int m = 0; m < 4; ++m)
      af[m] = *(const bf16x8_t*)(&As[cur][(((wr << 6) + (m << 4) + lr) << 5) + sw]);
#pragma unroll
    for (int n = 0; n < 4; ++n)
      bfm[n] = *(const bf16x8_t*)(&Bs[cur][(((wc << 6) + (n << 4) + lr) << 5) + sw]);
#pragma unroll
    for (int m = 0; m < 4; ++m)
#pragma unroll
      for (int n = 0; n < 4; ++n)
        acc[m][n] = __builtin_amdgcn_mfma_f32_16x16x32_bf16(af[m], bfm[n], acc[m][n], 0, 0, 0);

    __syncthreads();
    cur ^= 1;
  }

  const int rowbase = m0 + (wr << 6) + (lh << 2);
  const int colbase = n0 + (wc << 6) + lr;
#pragma unroll
  for (int m = 0; m < 4; ++m) {
#pragma unroll
    for (int n = 0; n < 4; ++n) {
      const f32x4 v = acc[m][n];
      const int cc = colbase + (n << 4);
#pragma unroll
      for (int r = 0; r < 4; ++r) {
        const int rr = rowbase + (m << 4) + r;
        const float val = v[r];
        if constexpr (MODE == 0) {
          const float b = (cc < 64) ? aux0[cc] : aux1[cc - 64];
          const float s = (cc < 64) ? 0.125f : 1.0f;
          ((bf16_t*)Cv)[(long)rr * ldc + cc] = (bf16_t)((val + b) * s);
        } else {
          const float zz = val + a0[rr];
          const float e = __expf(-zz);                       // v_exp path
          const float sg = __builtin_amdgcn_rcpf(1.0f + e);  // v_rcp_f32
          ((bf16_t*)Cv)[(long)bz * sCb + (long)rr * ldc + cc] = (bf16_t)sg;
        }
      }
    }
  }
}

// ---------------------------------------------------------------------------
__global__ __launch_bounds__(256) void cast_bf16_kernel(
    const float* __restrict__ in, bf16_t* __restrict__ out, long n) {
  long i = ((long)blockIdx.x * 256 + threadIdx.x) * 4;
  const long step = (long)gridDim.x * 1024;
  for (; i < n; i += step) {
    const float4 v = *(const float4*)(in + i);
    bf16x4_t o;
    o[0] = (bf16_t)v.x; o[1] = (bf16_t)v.y; o[2] = (bf16_t)v.z; o[3] = (bf16_t)v.w;
    *(bf16x4_t*)(out + i) = o;
  }
}

__global__ __launch_bounds__(256) void transpose_cast_kernel(
    const float* __restrict__ in, bf16_t* __restrict__ out, int R, int C) {
  __shared__ float t[32][33];
  const int c0 = blockIdx.x * 32, r0 = blockIdx.y * 32;
  const int tx = threadIdx.x & 31, ty = threadIdx.x >> 5;
#pragma unroll
  for (int i = 0; i < 4; ++i) {
    const int rl = ty * 4 + i;
    t[rl][tx] = in[(long)(r0 + rl) * C + c0 + tx];
  }
  __syncthreads();
#pragma unroll
  for (int i = 0; i < 4; ++i) {
    const int rl = ty * 4 + i;
    out[(long)(c0 + rl) * R + r0 + tx] = (bf16_t)t[tx][rl];
  }
}

__global__ __launch_bounds__(256) void bias_kernel(
    const bf16_t* __restrict__ x, const float* __restrict__ Wb,
    const float* __restrict__ bb, float* __restrict__ biases) {
  const int r = blockIdx.x * 4 + (threadIdx.x >> 6);
  const int l = threadIdx.x & 63;
  const bf16_t* xr = x + (long)r * 1024;
  float s = 0.f;
#pragma unroll
  for (int i = 0; i < 8; ++i) {
    const bf16x2_t v = *(const bf16x2_t*)(xr + (l << 1) + (i << 7));
    const float2 wv = *(const float2*)(Wb + (l << 1) + (i << 7));
    s += (float)v[0] * wv.x + (float)v[1] * wv.y;
  }
#pragma unroll
  for (int off = 1; off < 64; off <<= 1) s += __shfl_xor(s, off);
  if (l == 0) biases[r] = s + bb[0];
}

DEV float2 block_sum2(float s, float ss) {
#pragma unroll
  for (int off = 1; off < 64; off <<= 1) {
    s += __shfl_xor(s, off);
    ss += __shfl_xor(ss, off);
  }
  __shared__ float bs[4], bss[4];
  const int w = threadIdx.x >> 6, l = threadIdx.x & 63;
  if (l == 0) { bs[w] = s; bss[w] = ss; }
  __syncthreads();
  s = bs[0] + bs[1] + bs[2] + bs[3];
  ss = bss[0] + bss[1] + bss[2] + bss[3];
  return make_float2(s, ss);
}

__global__ __launch_bounds__(256) void ln1_kernel(
    const bf16_t* __restrict__ x, const bf16_t* __restrict__ attn,
    const float* __restrict__ g, const float* __restrict__ be,
    bf16_t* __restrict__ res) {
  const long r = blockIdx.x;
  const int t = threadIdx.x;
  const bf16x4_t xv = *(const bf16x4_t*)(x + r * 1024 + t * 4);
  const bf16x4_t av = *(const bf16x4_t*)(attn + r * 1024 + t * 4);
  const float y0 = (float)xv[0] + (float)av[0], y1 = (float)xv[1] + (float)av[1];
  const float y2 = (float)xv[2] + (float)av[2], y3 = (float)xv[3] + (float)av[3];
  const float2 s2 = block_sum2(y0 + y1 + y2 + y3, y0 * y0 + y1 * y1 + y2 * y2 + y3 * y3);
  const float mean = s2.x * (1.0f / 1024.0f);
  const float var = s2.y * (1.0f / 1024.0f) - mean * mean;
  const float rs = rsqrtf(var + 1e-5f);
  const int c = t * 4;
  bf16x4_t o;
  o[0] = (bf16_t)((y0 - mean) * rs * g[c + 0] + be[c + 0]);
  o[1] = (bf16_t)((y1 - mean) * rs * g[c + 1] + be[c + 1]);
  o[2] = (bf16_t)((y2 - mean) * rs * g[c + 2] + be[c + 2]);
  o[3] = (bf16_t)((y3 - mean) * rs * g[c + 3] + be[c + 3]);
  *(bf16x4_t*)(res + r * 1024 + c) = o;
}

__global__ __launch_bounds__(256) void ln2_kernel(
    const bf16_t* __restrict__ res, const bf16_t* __restrict__ h,
    float* __restrict__ out) {
  const long r = blockIdx.x;
  const int t = threadIdx.x;
  const bf16x4_t rv = *(const bf16x4_t*)(res + r * 1024 + t * 4);
  const bf16x4_t hv = *(const bf16x4_t*)(h + r * 1024 + t * 4);
  const float y0 = (float)rv[0] + (float)hv[0], y1 = (float)rv[1] + (float)hv[1];
  const float y2 = (float)rv[2] + (float)hv[2], y3 = (float)rv[3] + (float)hv[3];
  const float2 s2 = block_sum2(y0 + y1 + y2 + y3, y0 * y0 + y1 * y1 + y2 * y2 + y3 * y3);
  const float mean = s2.x * (1.0f / 1024.0f);
  const float var = s2.y * (1.0f / 1024.0f) - mean * mean;
  const float rs = rsqrtf(var + 1e-5f);
  float4 o;
  o.x = (y0 - mean) * rs; o.y = (y1 - mean) * rs;
  o.z = (y2 - mean) * rs; o.w = (y3 - mean) * rs;
  ((float4*)(out + r * 1024))[t] = o;
}

// ---------------------------------------------------------------------------
extern "C" void kernel_launch(void* const* d_in, const int* in_sizes, int n_in,
                              void* d_out, int out_size, void* d_ws, size_t ws_size,
                              hipStream_t stream) {
  const float* x   = (const float*)d_in[0];
  const float* Wk  = (const float*)d_in[1];
  const float* bk  = (const float*)d_in[2];
  const float* Wq  = (const float*)d_in[3];
  const float* bq  = (const float*)d_in[4];
  const float* Wv  = (const float*)d_in[5];
  const float* bv  = (const float*)d_in[6];
  const float* Wb  = (const float*)d_in[7];
  const float* bb  = (const float*)d_in[8];
  const float* W1  = (const float*)d_in[9];
  const float* b1  = (const float*)d_in[10];
  const float* g1  = (const float*)d_in[11];
  const float* be1 = (const float*)d_in[12];
  float* out = (float*)d_out;

  char* ws = (char*)d_ws;
  bf16_t* x_bf    = (bf16_t*)(ws + 0);           //  32 MB  [16384][1024]
  bf16_t* vt_bf   = (bf16_t*)(ws + 33554432);    //  32 MB  V^T [1024][16384]
  bf16_t* kq_bf   = (bf16_t*)(ws + 67108864);    //   4 MB  [16384][128]
  bf16_t* Wkqt    = (bf16_t*)(ws + 71303168);    // 256 KB  [128][1024]
  bf16_t* Wvt     = (bf16_t*)(ws + 71565312);    //   2 MB
  bf16_t* W1t     = (bf16_t*)(ws + 73662464);    //   2 MB
  float*  biases  = (float*) (ws + 75759616);    //  64 KB
  bf16_t* scores  = (bf16_t*)(ws + 75825152);    //  64 MB  [8][2048][2048]
  bf16_t* attn_bf = (bf16_t*)(ws + 142934016);   //  32 MB  [8][2048][1024]
  bf16_t* res_bf  = (bf16_t*)(ws + 176488448);   //  32 MB
  bf16_t* h_bf    = attn_bf;                     // alias: attn dead after ln1

  const long BS = 16384;

  cast_bf16_kernel<<<8192, 256, 0, stream>>>(x, x_bf, BS * 1024);
  transpose_cast_kernel<<<dim3(2, 32), 256, 0, stream>>>(Wk, Wkqt, 1024, 64);
  transpose_cast_kernel<<<dim3(2, 32), 256, 0, stream>>>(Wq, Wkqt + 64 * 1024, 1024, 64);
  transpose_cast_kernel<<<dim3(32, 32), 256, 0, stream>>>(Wv, Wvt, 1024, 1024);
  transpose_cast_kernel<<<dim3(32, 32), 256, 0, stream>>>(W1, W1t, 1024, 1024);
  bias_kernel<<<4096, 256, 0, stream>>>(x_bf, Wb, bb, biases);

  // keys|queries: [16384][128] (128x128 kernel, N=128)
  gemm_bt<0, 0><<<dim3(1, 128, 1), 256, 0, stream>>>(
      x_bf, Wkqt, kq_bf, 16384, 128, 1024, 1024, 1024, 128, 0, 0, 0, bk, bq, 0);

  // V^T = Wv^T @ x^T (+bv row bias): M=1024, N=16384, K=1024; MFAST
  gemm256<1, 1><<<dim3(64, 4, 1), 512, 0, stream>>>(
      Wvt, x_bf, vt_bf, 1024, 1024, 1024, 16384, 0, 0, 0, bv);

  // scores = sigmoid(keys.queries^T + bias_i), batched (K=64 -> 128x128 kernel)
  gemm_bt<2, 0><<<dim3(16, 16, 8), 256, 0, stream>>>(
      kq_bf, kq_bf + 64, scores, 2048, 2048, 64, 128, 128, 2048,
      2048L * 128, 2048L * 128, 2048L * 2048, biases, nullptr, 2048);

  // attn = scores @ V: M=2048, N=1024, K=2048, batch 8
  gemm256<3, 0><<<dim3(4, 8, 8), 512, 0, stream>>>(
      scores, vt_bf, attn_bf, 2048, 2048, 16384, 1024,
      2048L * 2048, 2048, 2048L * 1024, nullptr);

  // res = bf16(LN(x+attn)*g1+be1)
  ln1_kernel<<<16384, 256, 0, stream>>>(x_bf, attn_bf, g1, be1, res_bf);

  // h = relu(res @ W1 + b1): M=16384, N=1024, K=1024
  gemm256<4, 0><<<dim3(4, 64, 1), 512, 0, stream>>>(
      res_bf, W1t, h_bf, 1024, 1024, 1024, 1024, 0, 0, 0, b1);

  // out = LN(res + h)
  ln2_kernel<<<16384, 256, 0, stream>>>(res_bf, h_bf, out);
}

// Round 8
// 252.400 us; speedup vs baseline: 1.0837x; 1.0837x over previous
//
#include <hip/hip_runtime.h>
#include <math.h>

// ---------------------------------------------------------------------------
// AttentionEncoder: B=8, S=2048, D=1024, K=64
// Round 8: K-loop reverted to R6 (best measured). NEW: coalesced C epilogue —
// C-tile bounced through the dead As/Bs LDS (XOR-swizzled 2B writes, <=2-way)
// then streamed out as bf16x8 (1KB/instr). Scores kernel was the big loser
// (64MB of scalar 2B stores). Also: bias row-dot fused into the cast kernel.
// ---------------------------------------------------------------------------

typedef __bf16 bf16_t;
typedef __bf16 bf16x4_t __attribute__((ext_vector_type(4)));
typedef __bf16 bf16x8_t __attribute__((ext_vector_type(8)));
typedef float  f32x4    __attribute__((ext_vector_type(4)));

#define DEV static __device__ __forceinline__

DEV void gll16(const void* g, void* l) {
  __builtin_amdgcn_global_load_lds(
      (const __attribute__((address_space(1))) void*)g,
      (__attribute__((address_space(3))) void*)l, 16, 0, 0);
}

// ---------------------------------------------------------------------------
// 256x256 tile, BK=64, 512 threads (8 waves 2Mx4N), dbuf LDS, R6 schedule:
// 4 phases/K-tile, pre-barrier ds_reads, vmcnt(4) at P2/P4.
// MODE: 1 VT (bf16, +bv[row]) ; 3 ATTN (bf16) ; 4 FF (bf16, relu(+b1[col]))
// ---------------------------------------------------------------------------
template <int MODE, int MFAST>
__global__ __launch_bounds__(512, 2) void gemm256(
    const bf16_t* __restrict__ A, const bf16_t* __restrict__ B,
    bf16_t* __restrict__ C, int K, int lda, int ldb, int ldc,
    long sAb, long sBb, long sCb, const float* __restrict__ aux0) {
  const int gx = gridDim.x, gy = gridDim.y;
  const int gxy = gx * gy;
  const int nwg = gxy * (int)gridDim.z;
  const int orig = blockIdx.x + gx * blockIdx.y + gxy * blockIdx.z;
  const int lid = (orig & 7) * (nwg >> 3) + (orig >> 3);
  const int bz = lid / gxy;
  const int rem = lid - bz * gxy;
  const int bx = MFAST ? (rem / gy) : (rem % gx);
  const int by = MFAST ? (rem % gy) : (rem / gx);

  A += (long)bz * sAb;
  B += (long)bz * sBb;
  const int m0 = by * 256, n0 = bx * 256;

  // 128KB: As halves at 0..32K bf16, Bs at 32K..64K bf16; C-stage reuses all.
  __shared__ bf16_t SM[65536];
#define ASH(b, h) (&SM[(((b)*2 + (h)) << 13)])
#define BSH(b, h) (&SM[32768 + (((b)*2 + (h)) << 13)])

  const int tid = threadIdx.x;
  const int wid = tid >> 6, l = tid & 63;
  const int wr = wid >> 2, wc = wid & 3;   // 2x4 wave grid; wave tile 128x64
  const int lr = l & 15, lh = l >> 4;

  const int sRow = tid >> 2;
  const int sSl = (tid & 3) ^ ((tid >> 3) & 3);
  const bf16_t* Asrc = A + (long)(m0 + sRow) * lda + sSl * 8;
  const bf16_t* Bsrc = B + (long)(n0 + sRow) * ldb + sSl * 8;
  const long aStep = (long)128 * lda, bStep = (long)128 * ldb;

#define STAGE_A(b, h, kt) do { \
    const bf16_t* s_ = Asrc + (kt) * 64 + (h) * 32; \
    gll16(s_,         ASH(b, h) + tid * 8); \
    gll16(s_ + aStep, ASH(b, h) + 4096 + tid * 8); } while (0)
#define STAGE_B(b, h, kt) do { \
    const bf16_t* s_ = Bsrc + (kt) * 64 + (h) * 32; \
    gll16(s_,         BSH(b, h) + tid * 8); \
    gll16(s_ + bStep, BSH(b, h) + 4096 + tid * 8); } while (0)

  const int sw = (lh ^ ((lr >> 1) & 3)) * 8;
  const int aOff = (wr * 128 + lr) * 32 + sw;  // + m*512 per m-frag
  const int bOff = (wc * 64 + lr) * 32 + sw;   // + n*512 per n-frag

  f32x4 acc[8][4] = {};
  const int NT = K >> 6;

  STAGE_A(0, 0, 0); STAGE_B(0, 0, 0); STAGE_A(0, 1, 0); STAGE_B(0, 1, 0);
  asm volatile("s_waitcnt vmcnt(4)" ::: "memory");
  __builtin_amdgcn_s_barrier();

#define PHASE_SYNC() do { \
    __builtin_amdgcn_sched_barrier(0); \
    __builtin_amdgcn_s_barrier(); \
    asm volatile("s_waitcnt lgkmcnt(0)" ::: "memory"); \
    __builtin_amdgcn_sched_barrier(0); } while (0)
#define MFMA_LO() do { \
    __builtin_amdgcn_s_setprio(1); \
    _Pragma("unroll") for (int m = 0; m < 4; ++m) \
    _Pragma("unroll") for (int n = 0; n < 4; ++n) \
      acc[m][n] = __builtin_amdgcn_mfma_f32_16x16x32_bf16(aF[m], bF[n], acc[m][n], 0, 0, 0); \
    __builtin_amdgcn_s_setprio(0); } while (0)
#define MFMA_HI() do { \
    __builtin_amdgcn_s_setprio(1); \
    _Pragma("unroll") for (int m = 0; m < 4; ++m) \
    _Pragma("unroll") for (int n = 0; n < 4; ++n) \
      acc[m + 4][n] = __builtin_amdgcn_mfma_f32_16x16x32_bf16(aG[m], bF[n], acc[m + 4][n], 0, 0, 0); \
    __builtin_amdgcn_s_setprio(0); } while (0)

  for (int t = 0; t < NT; ++t) {
    const int p = t & 1, q = p ^ 1;
    const bool pf = (t + 1 < NT);
    bf16x8_t bF[4], aF[4], aG[4];

    // ---- P1 ----
#pragma unroll
    for (int n = 0; n < 4; ++n) bF[n] = *(const bf16x8_t*)(BSH(p, 0) + bOff + n * 512);
#pragma unroll
    for (int m = 0; m < 4; ++m) aF[m] = *(const bf16x8_t*)(ASH(p, 0) + aOff + m * 512);
    if (pf) STAGE_A(q, 0, t + 1);
    PHASE_SYNC();
    MFMA_LO();

    // ---- P2 ----
#pragma unroll
    for (int m = 0; m < 4; ++m) aG[m] = *(const bf16x8_t*)(ASH(p, 0) + aOff + (m + 4) * 512);
    if (pf) {
      STAGE_B(q, 0, t + 1);
      asm volatile("s_waitcnt vmcnt(4)" ::: "memory");
    } else {
      asm volatile("s_waitcnt vmcnt(0)" ::: "memory");
    }
    PHASE_SYNC();
    MFMA_HI();

    // ---- P3 ----
#pragma unroll
    for (int n = 0; n < 4; ++n) bF[n] = *(const bf16x8_t*)(BSH(p, 1) + bOff + n * 512);
#pragma unroll
    for (int m = 0; m < 4; ++m) aF[m] = *(const bf16x8_t*)(ASH(p, 1) + aOff + m * 512);
    if (pf) STAGE_A(q, 1, t + 1);
    PHASE_SYNC();
    MFMA_LO();

    // ---- P4 ----
#pragma unroll
    for (int m = 0; m < 4; ++m) aG[m] = *(const bf16x8_t*)(ASH(p, 1) + aOff + (m + 4) * 512);
    if (pf) STAGE_B(q, 1, t + 1);
    asm volatile("s_waitcnt vmcnt(4)" ::: "memory");
    PHASE_SYNC();
    MFMA_HI();
  }
#undef STAGE_A
#undef STAGE_B
#undef PHASE_SYNC
#undef MFMA_LO
#undef MFMA_HI

  // ---- coalesced epilogue via LDS bounce (SM = [256][256] bf16) ----
  __builtin_amdgcn_s_barrier();   // everyone done reading As/Bs
  {
    const int rowb = wr * 128 + lh * 4;   // local row base (g = lh)
    const int colb = wc * 64 + lr;
#pragma unroll
    for (int m = 0; m < 8; ++m)
#pragma unroll
      for (int n = 0; n < 4; ++n) {
        const f32x4 v = acc[m][n];
        const int cl = colb + n * 16;
#pragma unroll
        for (int r = 0; r < 4; ++r) {
          const int rl = rowb + m * 16 + r;
          float val = v[r];
          if constexpr (MODE == 1) val += aux0[m0 + rl];
          else if constexpr (MODE == 4) val = fmaxf(val + aux0[n0 + cl], 0.0f);
          SM[rl * 256 + (cl ^ (lh << 4))] = (bf16_t)val;
        }
      }
    __builtin_amdgcn_s_barrier();
    bf16_t* Cb = C + (long)bz * sCb;
    const int chunk = tid & 31, rsub = tid >> 5;
#pragma unroll
    for (int pp = 0; pp < 16; ++pp) {
      const int rl = pp * 16 + rsub;
      const int sc = chunk ^ (((rl >> 2) & 3) << 1);
      const bf16x8_t vv = *(const bf16x8_t*)&SM[rl * 256 + sc * 8];
      *(bf16x8_t*)&Cb[(long)(m0 + rl) * ldc + n0 + chunk * 8] = vv;
    }
  }
#undef ASH
#undef BSH
}

// ---------------------------------------------------------------------------
// 128x128 2-phase kernel (KQ, scores) with the same coalesced LDS epilogue.
// MODE 0: KQ -> bf16, col<64: (v+bk[col])*0.125 else v+bq[col-64]
// MODE 2: SCORE -> bf16, sigmoid(v + rowbias[z*sAux + row])
// ---------------------------------------------------------------------------
template <int MODE, int MFAST>
__global__ __launch_bounds__(256) void gemm_bt(
    const bf16_t* __restrict__ A, const bf16_t* __restrict__ B,
    void* __restrict__ Cv, int M, int N, int K, int lda, int ldb, int ldc,
    long sAb, long sBb, long sCb,
    const float* __restrict__ aux0, const float* __restrict__ aux1, long sAux) {
  const int gx = gridDim.x, gy = gridDim.y;
  const int gxy = gx * gy;
  const int nwg = gxy * (int)gridDim.z;
  const int orig = blockIdx.x + gx * blockIdx.y + gxy * blockIdx.z;
  const int q = nwg >> 3, r8 = nwg & 7;
  const int xcd = orig & 7, seq = orig >> 3;
  const int lid = (xcd < r8 ? xcd * (q + 1) : r8 * (q + 1) + (xcd - r8) * q) + seq;
  const int bz = lid / gxy;
  const int rem = lid - bz * gxy;
  const int bx = MFAST ? (rem / gy) : (rem % gx);
  const int by = MFAST ? (rem % gy) : (rem / gx);

  A += (long)bz * sAb;
  B += (long)bz * sBb;
  const float* a0 = (MODE == 2) ? (aux0 + (long)bz * sAux) : aux0;

  const int m0 = by * 128;
  const int n0 = bx * 128;

  __shared__ bf16_t SM[16384];   // As: 0..8K, Bs: 8K..16K; C-stage reuses all
#define ASH(b) (&SM[(b) << 12])
#define BSH(b) (&SM[8192 + ((b) << 12)])

  const int tid = threadIdx.x;
  const int w = tid >> 6, l = tid & 63;
  const int wr = w >> 1, wc = w & 1;
  const int lr = l & 15, lh = l >> 4;

  const int srow = l >> 2;
  const int scol = (((l & 3) ^ (srow & 3)) << 3);

  f32x4 acc[4][4] = {};

  auto stage = [&](int buf, int k0) {
#pragma unroll
    for (int half = 0; half < 2; ++half) {
      const int i = 2 * w + half;
      const int row = (i << 4) + srow;
      gll16(A + (long)(m0 + row) * lda + k0 + scol, ASH(buf) + (i << 9));
      gll16(B + (long)(n0 + row) * ldb + k0 + scol, BSH(buf) + (i << 9));
    }
  };

  stage(0, 0);
  __syncthreads();
  int cur = 0;
  const int sw = ((lh ^ (lr & 3)) << 3);

  for (int k0 = 0; k0 < K; k0 += 32) {
    if (k0 + 32 < K) stage(cur ^ 1, k0 + 32);

    bf16x8_t af[4], bfm[4];
#pragma unroll
    for (int m = 0; m < 4; ++m)
      af[m] = *(const bf16x8_t*)(ASH(cur) + (((wr << 6) + (m << 4) + lr) << 5) + sw);
#pragma unroll
    for (int n = 0; n < 4; ++n)
      bfm[n] = *(const bf16x8_t*)(BSH(cur) + (((wc << 6) + (n << 4) + lr) << 5) + sw);
#pragma unroll
    for (int m = 0; m < 4; ++m)
#pragma unroll
      for (int n = 0; n < 4; ++n)
        acc[m][n] = __builtin_amdgcn_mfma_f32_16x16x32_bf16(af[m], bfm[n], acc[m][n], 0, 0, 0);

    __syncthreads();
    cur ^= 1;
  }

  // ---- coalesced epilogue via LDS bounce (SM = [128][128] bf16) ----
  {
    const int rowb = (wr << 6) + (lh << 2);
    const int colb = (wc << 6) + lr;
#pragma unroll
    for (int m = 0; m < 4; ++m)
#pragma unroll
      for (int n = 0; n < 4; ++n) {
        const f32x4 v = acc[m][n];
        const int cl = colb + (n << 4);
#pragma unroll
        for (int r = 0; r < 4; ++r) {
          const int rl = rowb + (m << 4) + r;
          float val = v[r];
          if constexpr (MODE == 0) {
            const int cc = n0 + cl;
            const float b = (cc < 64) ? aux0[cc] : aux1[cc - 64];
            val = (cc < 64) ? (val + b) * 0.125f : (val + b);
          } else {
            const float zz = val + a0[m0 + rl];
            val = __builtin_amdgcn_rcpf(1.0f + __expf(-zz));
          }
          SM[rl * 128 + (cl ^ (lh << 4))] = (bf16_t)val;
        }
      }
    __syncthreads();
    bf16_t* Cb = (bf16_t*)Cv + (MODE == 2 ? (long)bz * sCb : 0L);
    const int chunk = tid & 15, rsub = tid >> 4;
#pragma unroll
    for (int pp = 0; pp < 8; ++pp) {
      const int rl = pp * 16 + rsub;
      const int sc = chunk ^ (((rl >> 2) & 3) << 1);
      const bf16x8_t vv = *(const bf16x8_t*)&SM[rl * 128 + sc * 8];
      *(bf16x8_t*)&Cb[(long)(m0 + rl) * ldc + n0 + chunk * 8] = vv;
    }
  }
#undef ASH
#undef BSH
}

// ---------------------------------------------------------------------------
// fused cast + per-row bias dot: x_bf = bf16(x); biases[r] = x[r,:].Wb + bb
__global__ __launch_bounds__(256) void cast_bias_kernel(
    const float* __restrict__ x, const float* __restrict__ Wb,
    const float* __restrict__ bb, bf16_t* __restrict__ x_bf,
    float* __restrict__ biases) {
  const int r = blockIdx.x * 4 + (threadIdx.x >> 6);
  const int l = threadIdx.x & 63;
  const float* xr = x + (long)r * 1024;
  bf16_t* orow = x_bf + (long)r * 1024;
  float s = 0.f;
#pragma unroll
  for (int i = 0; i < 4; ++i) {
    const int off = l * 4 + i * 256;
    const float4 v = *(const float4*)(xr + off);
    const float4 w = *(const float4*)(Wb + off);
    s += v.x * w.x + v.y * w.y + v.z * w.z + v.w * w.w;
    bf16x4_t o;
    o[0] = (bf16_t)v.x; o[1] = (bf16_t)v.y; o[2] = (bf16_t)v.z; o[3] = (bf16_t)v.w;
    *(bf16x4_t*)(orow + off) = o;
  }
#pragma unroll
  for (int off = 1; off < 64; off <<= 1) s += __shfl_xor(s, off);
  if (l == 0) biases[r] = s + bb[0];
}

__global__ __launch_bounds__(256) void transpose_cast_kernel(
    const float* __restrict__ in, bf16_t* __restrict__ out, int R, int C) {
  __shared__ float t[32][33];
  const int c0 = blockIdx.x * 32, r0 = blockIdx.y * 32;
  const int tx = threadIdx.x & 31, ty = threadIdx.x >> 5;
#pragma unroll
  for (int i = 0; i < 4; ++i) {
    const int rl = ty * 4 + i;
    t[rl][tx] = in[(long)(r0 + rl) * C + c0 + tx];
  }
  __syncthreads();
#pragma unroll
  for (int i = 0; i < 4; ++i) {
    const int rl = ty * 4 + i;
    out[(long)(c0 + rl) * R + r0 + tx] = (bf16_t)t[tx][rl];
  }
}

DEV float2 block_sum2(float s, float ss) {
#pragma unroll
  for (int off = 1; off < 64; off <<= 1) {
    s += __shfl_xor(s, off);
    ss += __shfl_xor(ss, off);
  }
  __shared__ float bs[4], bss[4];
  const int w = threadIdx.x >> 6, l = threadIdx.x & 63;
  if (l == 0) { bs[w] = s; bss[w] = ss; }
  __syncthreads();
  s = bs[0] + bs[1] + bs[2] + bs[3];
  ss = bss[0] + bss[1] + bss[2] + bss[3];
  return make_float2(s, ss);
}

__global__ __launch_bounds__(256) void ln1_kernel(
    const bf16_t* __restrict__ x, const bf16_t* __restrict__ attn,
    const float* __restrict__ g, const float* __restrict__ be,
    bf16_t* __restrict__ res) {
  const long r = blockIdx.x;
  const int t = threadIdx.x;
  const bf16x4_t xv = *(const bf16x4_t*)(x + r * 1024 + t * 4);
  const bf16x4_t av = *(const bf16x4_t*)(attn + r * 1024 + t * 4);
  const float y0 = (float)xv[0] + (float)av[0], y1 = (float)xv[1] + (float)av[1];
  const float y2 = (float)xv[2] + (float)av[2], y3 = (float)xv[3] + (float)av[3];
  const float2 s2 = block_sum2(y0 + y1 + y2 + y3, y0 * y0 + y1 * y1 + y2 * y2 + y3 * y3);
  const float mean = s2.x * (1.0f / 1024.0f);
  const float var = s2.y * (1.0f / 1024.0f) - mean * mean;
  const float rs = rsqrtf(var + 1e-5f);
  const int c = t * 4;
  bf16x4_t o;
  o[0] = (bf16_t)((y0 - mean) * rs * g[c + 0] + be[c + 0]);
  o[1] = (bf16_t)((y1 - mean) * rs * g[c + 1] + be[c + 1]);
  o[2] = (bf16_t)((y2 - mean) * rs * g[c + 2] + be[c + 2]);
  o[3] = (bf16_t)((y3 - mean) * rs * g[c + 3] + be[c + 3]);
  *(bf16x4_t*)(res + r * 1024 + c) = o;
}

__global__ __launch_bounds__(256) void ln2_kernel(
    const bf16_t* __restrict__ res, const bf16_t* __restrict__ h,
    float* __restrict__ out) {
  const long r = blockIdx.x;
  const int t = threadIdx.x;
  const bf16x4_t rv = *(const bf16x4_t*)(res + r * 1024 + t * 4);
  const bf16x4_t hv = *(const bf16x4_t*)(h + r * 1024 + t * 4);
  const float y0 = (float)rv[0] + (float)hv[0], y1 = (float)rv[1] + (float)hv[1];
  const float y2 = (float)rv[2] + (float)hv[2], y3 = (float)rv[3] + (float)hv[3];
  const float2 s2 = block_sum2(y0 + y1 + y2 + y3, y0 * y0 + y1 * y1 + y2 * y2 + y3 * y3);
  const float mean = s2.x * (1.0f / 1024.0f);
  const float var = s2.y * (1.0f / 1024.0f) - mean * mean;
  const float rs = rsqrtf(var + 1e-5f);
  float4 o;
  o.x = (y0 - mean) * rs; o.y = (y1 - mean) * rs;
  o.z = (y2 - mean) * rs; o.w = (y3 - mean) * rs;
  ((float4*)(out + r * 1024))[t] = o;
}

// ---------------------------------------------------------------------------
extern "C" void kernel_launch(void* const* d_in, const int* in_sizes, int n_in,
                              void* d_out, int out_size, void* d_ws, size_t ws_size,
                              hipStream_t stream) {
  const float* x   = (const float*)d_in[0];
  const float* Wk  = (const float*)d_in[1];
  const float* bk  = (const float*)d_in[2];
  const float* Wq  = (const float*)d_in[3];
  const float* bq  = (const float*)d_in[4];
  const float* Wv  = (const float*)d_in[5];
  const float* bv  = (const float*)d_in[6];
  const float* Wb  = (const float*)d_in[7];
  const float* bb  = (const float*)d_in[8];
  const float* W1  = (const float*)d_in[9];
  const float* b1  = (const float*)d_in[10];
  const float* g1  = (const float*)d_in[11];
  const float* be1 = (const float*)d_in[12];
  float* out = (float*)d_out;

  char* ws = (char*)d_ws;
  bf16_t* x_bf    = (bf16_t*)(ws + 0);           //  32 MB  [16384][1024]
  bf16_t* vt_bf   = (bf16_t*)(ws + 33554432);    //  32 MB  V^T [1024][16384]
  bf16_t* kq_bf   = (bf16_t*)(ws + 67108864);    //   4 MB  [16384][128]
  bf16_t* Wkqt    = (bf16_t*)(ws + 71303168);    // 256 KB  [128][1024]
  bf16_t* Wvt     = (bf16_t*)(ws + 71565312);    //   2 MB
  bf16_t* W1t     = (bf16_t*)(ws + 73662464);    //   2 MB
  float*  biases  = (float*) (ws + 75759616);    //  64 KB
  bf16_t* scores  = (bf16_t*)(ws + 75825152);    //  64 MB  [8][2048][2048]
  bf16_t* attn_bf = (bf16_t*)(ws + 142934016);   //  32 MB  [8][2048][1024]
  bf16_t* res_bf  = (bf16_t*)(ws + 176488448);   //  32 MB
  bf16_t* h_bf    = attn_bf;                     // alias: attn dead after ln1

  cast_bias_kernel<<<4096, 256, 0, stream>>>(x, Wb, bb, x_bf, biases);
  transpose_cast_kernel<<<dim3(2, 32), 256, 0, stream>>>(Wk, Wkqt, 1024, 64);
  transpose_cast_kernel<<<dim3(2, 32), 256, 0, stream>>>(Wq, Wkqt + 64 * 1024, 1024, 64);
  transpose_cast_kernel<<<dim3(32, 32), 256, 0, stream>>>(Wv, Wvt, 1024, 1024);
  transpose_cast_kernel<<<dim3(32, 32), 256, 0, stream>>>(W1, W1t, 1024, 1024);

  // keys|queries: [16384][128] (128x128 kernel, N=128)
  gemm_bt<0, 0><<<dim3(1, 128, 1), 256, 0, stream>>>(
      x_bf, Wkqt, kq_bf, 16384, 128, 1024, 1024, 1024, 128, 0, 0, 0, bk, bq, 0);

  // V^T = Wv^T @ x^T (+bv row bias): M=1024, N=16384, K=1024; MFAST
  gemm256<1, 1><<<dim3(64, 4, 1), 512, 0, stream>>>(
      Wvt, x_bf, vt_bf, 1024, 1024, 1024, 16384, 0, 0, 0, bv);

  // scores = sigmoid(keys.queries^T + bias_i), batched (K=64 -> 128x128 kernel)
  gemm_bt<2, 0><<<dim3(16, 16, 8), 256, 0, stream>>>(
      kq_bf, kq_bf + 64, scores, 2048, 2048, 64, 128, 128, 2048,
      2048L * 128, 2048L * 128, 2048L * 2048, biases, nullptr, 2048);

  // attn = scores @ V: M=2048, N=1024, K=2048, batch 8
  gemm256<3, 0><<<dim3(4, 8, 8), 512, 0, stream>>>(
      scores, vt_bf, attn_bf, 2048, 2048, 16384, 1024,
      2048L * 2048, 2048, 2048L * 1024, nullptr);

  // res = bf16(LN(x+attn)*g1+be1)
  ln1_kernel<<<16384, 256, 0, stream>>>(x_bf, attn_bf, g1, be1, res_bf);

  // h = relu(res @ W1 + b1): M=16384, N=1024, K=1024
  gemm256<4, 0><<<dim3(4, 64, 1), 512, 0, stream>>>(
      res_bf, W1t, h_bf, 1024, 1024, 1024, 1024, 0, 0, 0, b1);

  // out = LN(res + h)
  ln2_kernel<<<16384, 256, 0, stream>>>(res_bf, h_bf, out);
}

// Round 9
// 241.644 us; speedup vs baseline: 1.1320x; 1.0445x over previous
//
#include <hip/hip_runtime.h>
#include <math.h>

// ---------------------------------------------------------------------------
// AttentionEncoder: B=8, S=2048, D=1024, K=64
// Round 9: (a) gemm256 epilogue reverted to R6 direct stores (bounce cost
// ~1.5us x3 on 1-block/CU kernels); (b) NEW kq_thin kernel for the KQ GEMM:
// BM=64 x BN=128 -> 256 blocks (was 128 -> half chip idle), 24KB LDS,
// multiple blocks/CU so TLP hides the lockstep barriers.
// ---------------------------------------------------------------------------

typedef __bf16 bf16_t;
typedef __bf16 bf16x4_t __attribute__((ext_vector_type(4)));
typedef __bf16 bf16x8_t __attribute__((ext_vector_type(8)));
typedef float  f32x4    __attribute__((ext_vector_type(4)));

#define DEV static __device__ __forceinline__

DEV void gll16(const void* g, void* l) {
  __builtin_amdgcn_global_load_lds(
      (const __attribute__((address_space(1))) void*)g,
      (__attribute__((address_space(3))) void*)l, 16, 0, 0);
}

// ---------------------------------------------------------------------------
// 256x256 tile, BK=64, 512 threads (8 waves 2Mx4N), dbuf LDS, R6 schedule:
// 4 phases/K-tile, pre-barrier ds_reads, vmcnt(4) at P2/P4, direct C stores.
// MODE: 1 VT (bf16, +bv[row]) ; 3 ATTN (bf16) ; 4 FF (bf16, relu(+b1[col]))
// ---------------------------------------------------------------------------
template <int MODE, int MFAST>
__global__ __launch_bounds__(512, 2) void gemm256(
    const bf16_t* __restrict__ A, const bf16_t* __restrict__ B,
    bf16_t* __restrict__ C, int K, int lda, int ldb, int ldc,
    long sAb, long sBb, long sCb, const float* __restrict__ aux0) {
  const int gx = gridDim.x, gy = gridDim.y;
  const int gxy = gx * gy;
  const int nwg = gxy * (int)gridDim.z;
  const int orig = blockIdx.x + gx * blockIdx.y + gxy * blockIdx.z;
  const int lid = (orig & 7) * (nwg >> 3) + (orig >> 3);
  const int bz = lid / gxy;
  const int rem = lid - bz * gxy;
  const int bx = MFAST ? (rem / gy) : (rem % gx);
  const int by = MFAST ? (rem % gy) : (rem / gx);

  A += (long)bz * sAb;
  B += (long)bz * sBb;
  const int m0 = by * 256, n0 = bx * 256;

  __shared__ bf16_t SM[65536];
#define ASH(b, h) (&SM[(((b)*2 + (h)) << 13)])
#define BSH(b, h) (&SM[32768 + (((b)*2 + (h)) << 13)])

  const int tid = threadIdx.x;
  const int wid = tid >> 6, l = tid & 63;
  const int wr = wid >> 2, wc = wid & 3;   // 2x4 wave grid; wave tile 128x64
  const int lr = l & 15, lh = l >> 4;

  const int sRow = tid >> 2;
  const int sSl = (tid & 3) ^ ((tid >> 3) & 3);
  const bf16_t* Asrc = A + (long)(m0 + sRow) * lda + sSl * 8;
  const bf16_t* Bsrc = B + (long)(n0 + sRow) * ldb + sSl * 8;
  const long aStep = (long)128 * lda, bStep = (long)128 * ldb;

#define STAGE_A(b, h, kt) do { \
    const bf16_t* s_ = Asrc + (kt) * 64 + (h) * 32; \
    gll16(s_,         ASH(b, h) + tid * 8); \
    gll16(s_ + aStep, ASH(b, h) + 4096 + tid * 8); } while (0)
#define STAGE_B(b, h, kt) do { \
    const bf16_t* s_ = Bsrc + (kt) * 64 + (h) * 32; \
    gll16(s_,         BSH(b, h) + tid * 8); \
    gll16(s_ + bStep, BSH(b, h) + 4096 + tid * 8); } while (0)

  const int sw = (lh ^ ((lr >> 1) & 3)) * 8;
  const int aOff = (wr * 128 + lr) * 32 + sw;  // + m*512 per m-frag
  const int bOff = (wc * 64 + lr) * 32 + sw;   // + n*512 per n-frag

  f32x4 acc[8][4] = {};
  const int NT = K >> 6;

  STAGE_A(0, 0, 0); STAGE_B(0, 0, 0); STAGE_A(0, 1, 0); STAGE_B(0, 1, 0);
  asm volatile("s_waitcnt vmcnt(4)" ::: "memory");
  __builtin_amdgcn_s_barrier();

#define PHASE_SYNC() do { \
    __builtin_amdgcn_sched_barrier(0); \
    __builtin_amdgcn_s_barrier(); \
    asm volatile("s_waitcnt lgkmcnt(0)" ::: "memory"); \
    __builtin_amdgcn_sched_barrier(0); } while (0)
#define MFMA_LO() do { \
    __builtin_amdgcn_s_setprio(1); \
    _Pragma("unroll") for (int m = 0; m < 4; ++m) \
    _Pragma("unroll") for (int n = 0; n < 4; ++n) \
      acc[m][n] = __builtin_amdgcn_mfma_f32_16x16x32_bf16(aF[m], bF[n], acc[m][n], 0, 0, 0); \
    __builtin_amdgcn_s_setprio(0); } while (0)
#define MFMA_HI() do { \
    __builtin_amdgcn_s_setprio(1); \
    _Pragma("unroll") for (int m = 0; m < 4; ++m) \
    _Pragma("unroll") for (int n = 0; n < 4; ++n) \
      acc[m + 4][n] = __builtin_amdgcn_mfma_f32_16x16x32_bf16(aG[m], bF[n], acc[m + 4][n], 0, 0, 0); \
    __builtin_amdgcn_s_setprio(0); } while (0)

  for (int t = 0; t < NT; ++t) {
    const int p = t & 1, q = p ^ 1;
    const bool pf = (t + 1 < NT);
    bf16x8_t bF[4], aF[4], aG[4];

    // ---- P1 ----
#pragma unroll
    for (int n = 0; n < 4; ++n) bF[n] = *(const bf16x8_t*)(BSH(p, 0) + bOff + n * 512);
#pragma unroll
    for (int m = 0; m < 4; ++m) aF[m] = *(const bf16x8_t*)(ASH(p, 0) + aOff + m * 512);
    if (pf) STAGE_A(q, 0, t + 1);
    PHASE_SYNC();
    MFMA_LO();

    // ---- P2 ----
#pragma unroll
    for (int m = 0; m < 4; ++m) aG[m] = *(const bf16x8_t*)(ASH(p, 0) + aOff + (m + 4) * 512);
    if (pf) {
      STAGE_B(q, 0, t + 1);
      asm volatile("s_waitcnt vmcnt(4)" ::: "memory");
    } else {
      asm volatile("s_waitcnt vmcnt(0)" ::: "memory");
    }
    PHASE_SYNC();
    MFMA_HI();

    // ---- P3 ----
#pragma unroll
    for (int n = 0; n < 4; ++n) bF[n] = *(const bf16x8_t*)(BSH(p, 1) + bOff + n * 512);
#pragma unroll
    for (int m = 0; m < 4; ++m) aF[m] = *(const bf16x8_t*)(ASH(p, 1) + aOff + m * 512);
    if (pf) STAGE_A(q, 1, t + 1);
    PHASE_SYNC();
    MFMA_LO();

    // ---- P4 ----
#pragma unroll
    for (int m = 0; m < 4; ++m) aG[m] = *(const bf16x8_t*)(ASH(p, 1) + aOff + (m + 4) * 512);
    if (pf) STAGE_B(q, 1, t + 1);
    asm volatile("s_waitcnt vmcnt(4)" ::: "memory");
    PHASE_SYNC();
    MFMA_HI();
  }
#undef STAGE_A
#undef STAGE_B
#undef PHASE_SYNC
#undef MFMA_LO
#undef MFMA_HI

  // epilogue (R6): direct stores. C/D frag col=lane&15, row=(lane>>4)*4+r
  bf16_t* Cb = C + (long)bz * sCb;
  const int rowb = m0 + wr * 128 + lh * 4;
  const int colb = n0 + wc * 64 + lr;
#pragma unroll
  for (int m = 0; m < 8; ++m)
#pragma unroll
    for (int n = 0; n < 4; ++n) {
      const f32x4 v = acc[m][n];
      const int cc = colb + n * 16;
#pragma unroll
      for (int r = 0; r < 4; ++r) {
        const int rr = rowb + m * 16 + r;
        const float val = v[r];
        if constexpr (MODE == 1) {
          Cb[(long)rr * ldc + cc] = (bf16_t)(val + aux0[rr]);
        } else if constexpr (MODE == 3) {
          Cb[(long)rr * ldc + cc] = (bf16_t)val;
        } else {
          Cb[(long)rr * ldc + cc] = (bf16_t)fmaxf(val + aux0[cc], 0.0f);
        }
      }
    }
#undef ASH
#undef BSH
}

// ---------------------------------------------------------------------------
// Thin-N kernel for KQ: C[16384][128] = x_bf * Wkqt^T, 64x128 tile, 256
// blocks. 4 waves; wave w owns rows w*16..+15 x all 128 cols (8 n-frags).
// Epilogue: bias+scale, LDS bounce, bf16x8 coalesced stores.
// ---------------------------------------------------------------------------
__global__ __launch_bounds__(256) void kq_thin(
    const bf16_t* __restrict__ A, const bf16_t* __restrict__ B,
    bf16_t* __restrict__ C,
    const float* __restrict__ bk, const float* __restrict__ bq) {
  const int m0 = blockIdx.x * 64;

  __shared__ bf16_t SM[12288];   // As: 2x2048, Bs: 2x4096 (24KB); C bounce 16KB
#define ASH(b) (&SM[(b) << 11])
#define BSH(b) (&SM[4096 + ((b) << 12)])

  const int tid = threadIdx.x;
  const int w = tid >> 6, l = tid & 63;
  const int lr = l & 15, lh = l >> 4;

  const int sRow = tid >> 2;                      // 0..63
  const int sSl = (tid & 3) ^ ((tid >> 3) & 3);   // pre-swizzled source slot
  const bf16_t* Asrc = A + (long)(m0 + sRow) * 1024 + sSl * 8;
  const bf16_t* Bsrc0 = B + (long)sRow * 1024 + sSl * 8;
  const bf16_t* Bsrc1 = B + (long)(64 + sRow) * 1024 + sSl * 8;

  const int sw = (lh ^ ((lr >> 1) & 3)) * 8;
  const int aOff = (w * 16 + lr) * 32 + sw;

  f32x4 acc[8] = {};

  auto stage = [&](int buf, int k0) {
    gll16(Asrc + k0, ASH(buf) + tid * 8);
    gll16(Bsrc0 + k0, BSH(buf) + tid * 8);
    gll16(Bsrc1 + k0, BSH(buf) + 2048 + tid * 8);
  };

  stage(0, 0);
  __syncthreads();
  int cur = 0;

  for (int k0 = 0; k0 < 1024; k0 += 32) {
    if (k0 + 32 < 1024) stage(cur ^ 1, k0 + 32);

    const bf16x8_t aF = *(const bf16x8_t*)(ASH(cur) + aOff);
    bf16x8_t bF[8];
#pragma unroll
    for (int j = 0; j < 8; ++j)
      bF[j] = *(const bf16x8_t*)(BSH(cur) + (j * 16 + lr) * 32 + sw);
#pragma unroll
    for (int j = 0; j < 8; ++j)
      acc[j] = __builtin_amdgcn_mfma_f32_16x16x32_bf16(aF, bF[j], acc[j], 0, 0, 0);

    __syncthreads();
    cur ^= 1;
  }

  // epilogue: bias+scale -> LDS bounce (64x128 bf16) -> coalesced stores
  {
#pragma unroll
    for (int j = 0; j < 8; ++j) {
      const f32x4 v = acc[j];
      const int cl = j * 16 + lr;
      const float b = (cl < 64) ? bk[cl] : bq[cl - 64];
      const float s = (cl < 64) ? 0.125f : 1.0f;
#pragma unroll
      for (int r = 0; r < 4; ++r) {
        const int rl = w * 16 + lh * 4 + r;
        SM[rl * 128 + (cl ^ (lh << 4))] = (bf16_t)((v[r] + b) * s);
      }
    }
    __syncthreads();
    const int chunk = tid & 15, rsub = tid >> 4;
#pragma unroll
    for (int pp = 0; pp < 4; ++pp) {
      const int rl = pp * 16 + rsub;
      const int sc = chunk ^ (((rl >> 2) & 3) << 1);
      const bf16x8_t vv = *(const bf16x8_t*)&SM[rl * 128 + sc * 8];
      *(bf16x8_t*)&C[(long)(m0 + rl) * 128 + chunk * 8] = vv;
    }
  }
#undef ASH
#undef BSH
}

// ---------------------------------------------------------------------------
// 128x128 2-phase kernel (scores) with coalesced LDS-bounce epilogue.
// MODE 2: SCORE -> bf16, sigmoid(v + rowbias[z*sAux + row])
// ---------------------------------------------------------------------------
template <int MODE, int MFAST>
__global__ __launch_bounds__(256) void gemm_bt(
    const bf16_t* __restrict__ A, const bf16_t* __restrict__ B,
    void* __restrict__ Cv, int M, int N, int K, int lda, int ldb, int ldc,
    long sAb, long sBb, long sCb,
    const float* __restrict__ aux0, const float* __restrict__ aux1, long sAux) {
  const int gx = gridDim.x, gy = gridDim.y;
  const int gxy = gx * gy;
  const int nwg = gxy * (int)gridDim.z;
  const int orig = blockIdx.x + gx * blockIdx.y + gxy * blockIdx.z;
  const int q = nwg >> 3, r8 = nwg & 7;
  const int xcd = orig & 7, seq = orig >> 3;
  const int lid = (xcd < r8 ? xcd * (q + 1) : r8 * (q + 1) + (xcd - r8) * q) + seq;
  const int bz = lid / gxy;
  const int rem = lid - bz * gxy;
  const int bx = MFAST ? (rem / gy) : (rem % gx);
  const int by = MFAST ? (rem % gy) : (rem / gx);

  A += (long)bz * sAb;
  B += (long)bz * sBb;
  const float* a0 = (MODE == 2) ? (aux0 + (long)bz * sAux) : aux0;

  const int m0 = by * 128;
  const int n0 = bx * 128;

  __shared__ bf16_t SM[16384];
#define ASH(b) (&SM[(b) << 12])
#define BSH(b) (&SM[8192 + ((b) << 12)])

  const int tid = threadIdx.x;
  const int w = tid >> 6, l = tid & 63;
  const int wr = w >> 1, wc = w & 1;
  const int lr = l & 15, lh = l >> 4;

  const int srow = l >> 2;
  const int scol = (((l & 3) ^ (srow & 3)) << 3);

  f32x4 acc[4][4] = {};

  auto stage = [&](int buf, int k0) {
#pragma unroll
    for (int half = 0; half < 2; ++half) {
      const int i = 2 * w + half;
      const int row = (i << 4) + srow;
      gll16(A + (long)(m0 + row) * lda + k0 + scol, ASH(buf) + (i << 9));
      gll16(B + (long)(n0 + row) * ldb + k0 + scol, BSH(buf) + (i << 9));
    }
  };

  stage(0, 0);
  __syncthreads();
  int cur = 0;
  const int sw = ((lh ^ (lr & 3)) << 3);

  for (int k0 = 0; k0 < K; k0 += 32) {
    if (k0 + 32 < K) stage(cur ^ 1, k0 + 32);

    bf16x8_t af[4], bfm[4];
#pragma unroll
    for (int m = 0; m < 4; ++m)
      af[m] = *(const bf16x8_t*)(ASH(cur) + (((wr << 6) + (m << 4) + lr) << 5) + sw);
#pragma unroll
    for (int n = 0; n < 4; ++n)
      bfm[n] = *(const bf16x8_t*)(BSH(cur) + (((wc << 6) + (n << 4) + lr) << 5) + sw);
#pragma unroll
    for (int m = 0; m < 4; ++m)
#pragma unroll
      for (int n = 0; n < 4; ++n)
        acc[m][n] = __builtin_amdgcn_mfma_f32_16x16x32_bf16(af[m], bfm[n], acc[m][n], 0, 0, 0);

    __syncthreads();
    cur ^= 1;
  }

  // coalesced epilogue via LDS bounce (SM = [128][128] bf16)
  {
    const int rowb = (wr << 6) + (lh << 2);
    const int colb = (wc << 6) + lr;
#pragma unroll
    for (int m = 0; m < 4; ++m)
#pragma unroll
      for (int n = 0; n < 4; ++n) {
        const f32x4 v = acc[m][n];
        const int cl = colb + (n << 4);
#pragma unroll
        for (int r = 0; r < 4; ++r) {
          const int rl = rowb + (m << 4) + r;
          const float zz = v[r] + a0[m0 + rl];
          SM[rl * 128 + (cl ^ (lh << 4))] =
              (bf16_t)__builtin_amdgcn_rcpf(1.0f + __expf(-zz));
        }
      }
    __syncthreads();
    bf16_t* Cb = (bf16_t*)Cv + (long)bz * sCb;
    const int chunk = tid & 15, rsub = tid >> 4;
#pragma unroll
    for (int pp = 0; pp < 8; ++pp) {
      const int rl = pp * 16 + rsub;
      const int sc = chunk ^ (((rl >> 2) & 3) << 1);
      const bf16x8_t vv = *(const bf16x8_t*)&SM[rl * 128 + sc * 8];
      *(bf16x8_t*)&Cb[(long)(m0 + rl) * ldc + n0 + chunk * 8] = vv;
    }
  }
#undef ASH
#undef BSH
}

// ---------------------------------------------------------------------------
__global__ __launch_bounds__(256) void cast_bias_kernel(
    const float* __restrict__ x, const float* __restrict__ Wb,
    const float* __restrict__ bb, bf16_t* __restrict__ x_bf,
    float* __restrict__ biases) {
  const int r = blockIdx.x * 4 + (threadIdx.x >> 6);
  const int l = threadIdx.x & 63;
  const float* xr = x + (long)r * 1024;
  bf16_t* orow = x_bf + (long)r * 1024;
  float s = 0.f;
#pragma unroll
  for (int i = 0; i < 4; ++i) {
    const int off = l * 4 + i * 256;
    const float4 v = *(const float4*)(xr + off);
    const float4 w = *(const float4*)(Wb + off);
    s += v.x * w.x + v.y * w.y + v.z * w.z + v.w * w.w;
    bf16x4_t o;
    o[0] = (bf16_t)v.x; o[1] = (bf16_t)v.y; o[2] = (bf16_t)v.z; o[3] = (bf16_t)v.w;
    *(bf16x4_t*)(orow + off) = o;
  }
#pragma unroll
  for (int off = 1; off < 64; off <<= 1) s += __shfl_xor(s, off);
  if (l == 0) biases[r] = s + bb[0];
}

__global__ __launch_bounds__(256) void transpose_cast_kernel(
    const float* __restrict__ in, bf16_t* __restrict__ out, int R, int C) {
  __shared__ float t[32][33];
  const int c0 = blockIdx.x * 32, r0 = blockIdx.y * 32;
  const int tx = threadIdx.x & 31, ty = threadIdx.x >> 5;
#pragma unroll
  for (int i = 0; i < 4; ++i) {
    const int rl = ty * 4 + i;
    t[rl][tx] = in[(long)(r0 + rl) * C + c0 + tx];
  }
  __syncthreads();
#pragma unroll
  for (int i = 0; i < 4; ++i) {
    const int rl = ty * 4 + i;
    out[(long)(c0 + rl) * R + r0 + tx] = (bf16_t)t[tx][rl];
  }
}

DEV float2 block_sum2(float s, float ss) {
#pragma unroll
  for (int off = 1; off < 64; off <<= 1) {
    s += __shfl_xor(s, off);
    ss += __shfl_xor(ss, off);
  }
  __shared__ float bs[4], bss[4];
  const int w = threadIdx.x >> 6, l = threadIdx.x & 63;
  if (l == 0) { bs[w] = s; bss[w] = ss; }
  __syncthreads();
  s = bs[0] + bs[1] + bs[2] + bs[3];
  ss = bss[0] + bss[1] + bss[2] + bss[3];
  return make_float2(s, ss);
}

__global__ __launch_bounds__(256) void ln1_kernel(
    const bf16_t* __restrict__ x, const bf16_t* __restrict__ attn,
    const float* __restrict__ g, const float* __restrict__ be,
    bf16_t* __restrict__ res) {
  const long r = blockIdx.x;
  const int t = threadIdx.x;
  const bf16x4_t xv = *(const bf16x4_t*)(x + r * 1024 + t * 4);
  const bf16x4_t av = *(const bf16x4_t*)(attn + r * 1024 + t * 4);
  const float y0 = (float)xv[0] + (float)av[0], y1 = (float)xv[1] + (float)av[1];
  const float y2 = (float)xv[2] + (float)av[2], y3 = (float)xv[3] + (float)av[3];
  const float2 s2 = block_sum2(y0 + y1 + y2 + y3, y0 * y0 + y1 * y1 + y2 * y2 + y3 * y3);
  const float mean = s2.x * (1.0f / 1024.0f);
  const float var = s2.y * (1.0f / 1024.0f) - mean * mean;
  const float rs = rsqrtf(var + 1e-5f);
  const int c = t * 4;
  bf16x4_t o;
  o[0] = (bf16_t)((y0 - mean) * rs * g[c + 0] + be[c + 0]);
  o[1] = (bf16_t)((y1 - mean) * rs * g[c + 1] + be[c + 1]);
  o[2] = (bf16_t)((y2 - mean) * rs * g[c + 2] + be[c + 2]);
  o[3] = (bf16_t)((y3 - mean) * rs * g[c + 3] + be[c + 3]);
  *(bf16x4_t*)(res + r * 1024 + c) = o;
}

__global__ __launch_bounds__(256) void ln2_kernel(
    const bf16_t* __restrict__ res, const bf16_t* __restrict__ h,
    float* __restrict__ out) {
  const long r = blockIdx.x;
  const int t = threadIdx.x;
  const bf16x4_t rv = *(const bf16x4_t*)(res + r * 1024 + t * 4);
  const bf16x4_t hv = *(const bf16x4_t*)(h + r * 1024 + t * 4);
  const float y0 = (float)rv[0] + (float)hv[0], y1 = (float)rv[1] + (float)hv[1];
  const float y2 = (float)rv[2] + (float)hv[2], y3 = (float)rv[3] + (float)hv[3];
  const float2 s2 = block_sum2(y0 + y1 + y2 + y3, y0 * y0 + y1 * y1 + y2 * y2 + y3 * y3);
  const float mean = s2.x * (1.0f / 1024.0f);
  const float var = s2.y * (1.0f / 1024.0f) - mean * mean;
  const float rs = rsqrtf(var + 1e-5f);
  float4 o;
  o.x = (y0 - mean) * rs; o.y = (y1 - mean) * rs;
  o.z = (y2 - mean) * rs; o.w = (y3 - mean) * rs;
  ((float4*)(out + r * 1024))[t] = o;
}

// ---------------------------------------------------------------------------
extern "C" void kernel_launch(void* const* d_in, const int* in_sizes, int n_in,
                              void* d_out, int out_size, void* d_ws, size_t ws_size,
                              hipStream_t stream) {
  const float* x   = (const float*)d_in[0];
  const float* Wk  = (const float*)d_in[1];
  const float* bk  = (const float*)d_in[2];
  const float* Wq  = (const float*)d_in[3];
  const float* bq  = (const float*)d_in[4];
  const float* Wv  = (const float*)d_in[5];
  const float* bv  = (const float*)d_in[6];
  const float* Wb  = (const float*)d_in[7];
  const float* bb  = (const float*)d_in[8];
  const float* W1  = (const float*)d_in[9];
  const float* b1  = (const float*)d_in[10];
  const float* g1  = (const float*)d_in[11];
  const float* be1 = (const float*)d_in[12];
  float* out = (float*)d_out;

  char* ws = (char*)d_ws;
  bf16_t* x_bf    = (bf16_t*)(ws + 0);           //  32 MB  [16384][1024]
  bf16_t* vt_bf   = (bf16_t*)(ws + 33554432);    //  32 MB  V^T [1024][16384]
  bf16_t* kq_bf   = (bf16_t*)(ws + 67108864);    //   4 MB  [16384][128]
  bf16_t* Wkqt    = (bf16_t*)(ws + 71303168);    // 256 KB  [128][1024]
  bf16_t* Wvt     = (bf16_t*)(ws + 71565312);    //   2 MB
  bf16_t* W1t     = (bf16_t*)(ws + 73662464);    //   2 MB
  float*  biases  = (float*) (ws + 75759616);    //  64 KB
  bf16_t* scores  = (bf16_t*)(ws + 75825152);    //  64 MB  [8][2048][2048]
  bf16_t* attn_bf = (bf16_t*)(ws + 142934016);   //  32 MB  [8][2048][1024]
  bf16_t* res_bf  = (bf16_t*)(ws + 176488448);   //  32 MB
  bf16_t* h_bf    = attn_bf;                     // alias: attn dead after ln1

  cast_bias_kernel<<<4096, 256, 0, stream>>>(x, Wb, bb, x_bf, biases);
  transpose_cast_kernel<<<dim3(2, 32), 256, 0, stream>>>(Wk, Wkqt, 1024, 64);
  transpose_cast_kernel<<<dim3(2, 32), 256, 0, stream>>>(Wq, Wkqt + 64 * 1024, 1024, 64);
  transpose_cast_kernel<<<dim3(32, 32), 256, 0, stream>>>(Wv, Wvt, 1024, 1024);
  transpose_cast_kernel<<<dim3(32, 32), 256, 0, stream>>>(W1, W1t, 1024, 1024);

  // keys|queries: [16384][128], thin-N kernel, 256 blocks
  kq_thin<<<256, 256, 0, stream>>>(x_bf, Wkqt, kq_bf, bk, bq);

  // V^T = Wv^T @ x^T (+bv row bias): M=1024, N=16384, K=1024; MFAST
  gemm256<1, 1><<<dim3(64, 4, 1), 512, 0, stream>>>(
      Wvt, x_bf, vt_bf, 1024, 1024, 1024, 16384, 0, 0, 0, bv);

  // scores = sigmoid(keys.queries^T + bias_i), batched (K=64 -> 128x128 kernel)
  gemm_bt<2, 0><<<dim3(16, 16, 8), 256, 0, stream>>>(
      kq_bf, kq_bf + 64, scores, 2048, 2048, 64, 128, 128, 2048,
      2048L * 128, 2048L * 128, 2048L * 2048, biases, nullptr, 2048);

  // attn = scores @ V: M=2048, N=1024, K=2048, batch 8
  gemm256<3, 0><<<dim3(4, 8, 8), 512, 0, stream>>>(
      scores, vt_bf, attn_bf, 2048, 2048, 16384, 1024,
      2048L * 2048, 2048, 2048L * 1024, nullptr);

  // res = bf16(LN(x+attn)*g1+be1)
  ln1_kernel<<<16384, 256, 0, stream>>>(x_bf, attn_bf, g1, be1, res_bf);

  // h = relu(res @ W1 + b1): M=16384, N=1024, K=1024
  gemm256<4, 0><<<dim3(4, 64, 1), 512, 0, stream>>>(
      res_bf, W1t, h_bf, 1024, 1024, 1024, 1024, 0, 0, 0, b1);

  // out = LN(res + h)
  ln2_kernel<<<16384, 256, 0, stream>>>(res_bf, h_bf, out);
}